// Round 1
// baseline (407.333 us; speedup 1.0000x reference)
//
#include <hip/hip_runtime.h>
#include <cmath>

typedef unsigned short u16;
typedef float floatx4 __attribute__((ext_vector_type(4)));
typedef short short8 __attribute__((ext_vector_type(8)));
typedef __bf16 bf16x8 __attribute__((ext_vector_type(8)));

#define GLOBAL_AS __attribute__((address_space(1)))
#define LDS_AS __attribute__((address_space(3)))

#define S_LEN 2048
#define D_MODEL 2048
#define NH 16
#define NKV 4
#define DHEAD 128
#define SM_SCALE 0.08838834764831843f

__device__ __forceinline__ u16 f2bf(float f) {
    unsigned int u = __builtin_bit_cast(unsigned int, f);
    u += 0x7fffu + ((u >> 16) & 1u);
    return (u16)(u >> 16);
}
__device__ __forceinline__ float bf2f(u16 x) {
    unsigned int u = ((unsigned int)x) << 16;
    return __builtin_bit_cast(float, u);
}
__device__ __forceinline__ floatx4 zf4() {
    floatx4 z; z[0] = 0.f; z[1] = 0.f; z[2] = 0.f; z[3] = 0.f; return z;
}
__device__ __forceinline__ floatx4 mfma16(short8 a, short8 b, floatx4 c) {
    return __builtin_amdgcn_mfma_f32_16x16x32_bf16(
        __builtin_bit_cast(bf16x8, a), __builtin_bit_cast(bf16x8, b), c, 0, 0, 0);
}
__device__ __forceinline__ void async16(const u16* g, u16* l) {
    __builtin_amdgcn_global_load_lds((GLOBAL_AS void*)g, (LDS_AS void*)l, 16, 0, 0);
}

// ---------------- cast X fp32 -> bf16 ----------------
__global__ void cast_x_kernel(const float4* __restrict__ in, ushort4* __restrict__ out) {
    int i = blockIdx.x * 256 + threadIdx.x;
    float4 v = in[i];
    ushort4 o;
    o.x = f2bf(v.x); o.y = f2bf(v.y); o.z = f2bf(v.z); o.w = f2bf(v.w);
    out[i] = o;
}

// ---------------- transpose + cast weights: in[R][C] fp32 -> out[C][R] bf16 ----------------
__global__ void transpose_cast_kernel(const float* __restrict__ in, u16* __restrict__ out,
                                      int R, int C) {
    __shared__ float tile[32][33];
    int tx = threadIdx.x & 31, ty = threadIdx.x >> 5;
    int bx = blockIdx.x * 32;  // over C
    int by = blockIdx.y * 32;  // over R
#pragma unroll
    for (int i = 0; i < 32; i += 8)
        tile[ty + i][tx] = in[(size_t)(by + ty + i) * C + bx + tx];
    __syncthreads();
#pragma unroll
    for (int i = 0; i < 32; i += 8)
        out[(size_t)(bx + ty + i) * R + by + tx] = f2bf(tile[tx][ty + i]);
}

// ---------------- rope tables (fp32-rounded angle, accurate trig) ----------------
__global__ void rope_tables_kernel(float* __restrict__ cs_tab, float* __restrict__ sn_tab) {
    int idx = blockIdx.x * 256 + threadIdx.x;  // 2048*64
    int p = idx >> 6, j = idx & 63;
    double e = (double)(2 * j) / 128.0;
    double invf = pow(10000.0, -e);
    float arg = (float)p * (float)invf;  // match reference's fp32 angle
    cs_tab[idx] = (float)cos((double)arg);
    sn_tab[idx] = (float)sin((double)arg);
}

// ---------------- apply RoPE in place on Q and K ----------------
__global__ void rope_apply_kernel(u16* __restrict__ Qb, u16* __restrict__ Kb,
                                  const int* __restrict__ pos,
                                  const float* __restrict__ cs_tab,
                                  const float* __restrict__ sn_tab) {
    int idx = blockIdx.x * 256 + threadIdx.x;  // 2*20*2048*64
    int j = idx & 63;
    int s = (idx >> 6) & 2047;
    int r = idx >> 17;        // b*20 + hh
    int hh = r % 20, b = r / 20;
    int p = pos[b * S_LEN + s];
    float cs = cs_tab[p * 64 + j], sn = sn_tab[p * 64 + j];
    u16* base;
    if (hh < 16) base = Qb + (((size_t)(b * NH + hh)) * S_LEN + s) * DHEAD;
    else         base = Kb + (((size_t)(b * NKV + (hh - 16))) * S_LEN + s) * DHEAD;
    float x1 = bf2f(base[j]), x2 = bf2f(base[j + 64]);
    base[j]      = f2bf(x1 * cs - x2 * sn);
    base[j + 64] = f2bf(x2 * cs + x1 * sn);
}

// ---------------- shared GEMM mainloop: A[M][K] bf16, Bt[N][K] bf16, 128x128 tile ----------------
__device__ __forceinline__ void gemm_mainloop(const u16* __restrict__ A,
                                              const u16* __restrict__ Bt,
                                              int K, u16* ldsA, u16* ldsB,
                                              floatx4 acc[4][4]) {
    const int t = threadIdx.x;
    const int lane = t & 63, wave = t >> 6;
    const int wr = wave >> 1, wc = wave & 1;
    const int lr = lane & 15, q = lane >> 4;
    const int m0 = blockIdx.y * 128, n0 = blockIdx.x * 128;

#pragma unroll
    for (int r = 0; r < 4; ++r)
#pragma unroll
        for (int c = 0; c < 4; ++c) acc[r][c] = zf4();

    for (int k0 = 0; k0 < K; k0 += 32) {
#pragma unroll
        for (int i = 0; i < 2; ++i) {
            int ci = i * 256 + t;
            int row = ci >> 2, kc = (ci & 3) << 3;
            async16(A + (size_t)(m0 + row) * K + k0 + kc, ldsA + (i * 256 + wave * 64) * 8);
            async16(Bt + (size_t)(n0 + row) * K + k0 + kc, ldsB + (i * 256 + wave * 64) * 8);
        }
        __syncthreads();
        short8 af[4], bf[4];
#pragma unroll
        for (int r = 0; r < 4; ++r)
            af[r] = *(const short8*)(ldsA + (wr * 64 + r * 16 + lr) * 32 + q * 8);
#pragma unroll
        for (int c = 0; c < 4; ++c)
            bf[c] = *(const short8*)(ldsB + (wc * 64 + c * 16 + lr) * 32 + q * 8);
#pragma unroll
        for (int r = 0; r < 4; ++r)
#pragma unroll
            for (int c = 0; c < 4; ++c)
                acc[r][c] = mfma16(af[r], bf[c], acc[r][c]);
        __syncthreads();
    }
}

// ---------------- QKV GEMM: scatter epilogue into Q/K/V^T bf16 ----------------
__global__ void qkv_gemm_kernel(const u16* __restrict__ A, const u16* __restrict__ Bt,
                                u16* __restrict__ Qb, u16* __restrict__ Kb,
                                u16* __restrict__ Vt) {
    __shared__ u16 ldsA[128 * 32];
    __shared__ u16 ldsB[128 * 32];
    floatx4 acc[4][4];
    gemm_mainloop(A, Bt, D_MODEL, ldsA, ldsB, acc);

    const int t = threadIdx.x, lane = t & 63, wave = t >> 6;
    const int wr = wave >> 1, wc = wave & 1, lr = lane & 15, q = lane >> 4;
    const int m0 = blockIdx.y * 128 + wr * 64, n0 = blockIdx.x * 128 + wc * 64;
#pragma unroll
    for (int r = 0; r < 4; ++r)
#pragma unroll
        for (int c = 0; c < 4; ++c) {
            int gc = n0 + c * 16 + lr;
#pragma unroll
            for (int rr = 0; rr < 4; ++rr) {
                int grow = m0 + r * 16 + q * 4 + rr;  // token
                int bb = grow >> 11, s = grow & 2047;
                u16 bv = f2bf(acc[r][c][rr]);
                int d = gc & 127;
                if (gc < 2048) {
                    int hh = gc >> 7;
                    Qb[(((size_t)(bb * NH + hh)) * S_LEN + s) * DHEAD + d] = bv;
                } else if (gc < 2560) {
                    int hh = (gc - 2048) >> 7;
                    Kb[(((size_t)(bb * NKV + hh)) * S_LEN + s) * DHEAD + d] = bv;
                } else {
                    int hh = (gc - 2560) >> 7;
                    Vt[(((size_t)(bb * NKV + hh)) * DHEAD + d) * S_LEN + s] = bv;
                }
            }
        }
}

// ---------------- out GEMM: fp32 epilogue to d_out ----------------
__global__ void out_gemm_kernel(const u16* __restrict__ A, const u16* __restrict__ Bt,
                                float* __restrict__ out) {
    __shared__ u16 ldsA[128 * 32];
    __shared__ u16 ldsB[128 * 32];
    floatx4 acc[4][4];
    gemm_mainloop(A, Bt, D_MODEL, ldsA, ldsB, acc);

    const int t = threadIdx.x, lane = t & 63, wave = t >> 6;
    const int wr = wave >> 1, wc = wave & 1, lr = lane & 15, q = lane >> 4;
    const int m0 = blockIdx.y * 128 + wr * 64, n0 = blockIdx.x * 128 + wc * 64;
#pragma unroll
    for (int r = 0; r < 4; ++r)
#pragma unroll
        for (int c = 0; c < 4; ++c) {
            int gc = n0 + c * 16 + lr;
#pragma unroll
            for (int rr = 0; rr < 4; ++rr) {
                int grow = m0 + r * 16 + q * 4 + rr;
                out[(size_t)grow * D_MODEL + gc] = acc[r][c][rr];
            }
        }
}

// ---------------- flash attention ----------------
// grid: 512 blocks = b(2) * h(16) * pair(16); each block does q-tiles {pair, 31-pair}
__global__ void fa_kernel(const u16* __restrict__ Qb, const u16* __restrict__ Kb,
                          const u16* __restrict__ Vt, u16* __restrict__ Ob) {
    __shared__ u16 ldsK[64 * 128];
    __shared__ u16 ldsV[128 * 64];
    __shared__ u16 ldsP[4 * 16 * 64];

    const int t = threadIdx.x, lane = t & 63, wave = t >> 6;
    const int lr = lane & 15, q = lane >> 4;

    const int bid = blockIdx.x;
    const int pair = bid & 15;
    const int h = (bid >> 4) & 15;
    const int b = bid >> 8;
    const int kvh = h >> 2;

    const u16* Kp = Kb + (size_t)(b * NKV + kvh) * S_LEN * DHEAD;
    const u16* Vp = Vt + (size_t)(b * NKV + kvh) * DHEAD * S_LEN;

    for (int which = 0; which < 2; ++which) {
        const int qt = (which == 0) ? pair : 31 - pair;
        const u16* Qp = Qb + ((size_t)((b * NH + h) * S_LEN) + qt * 64 + wave * 16) * DHEAD;

        short8 qf[4];
#pragma unroll
        for (int kk = 0; kk < 4; ++kk)
            qf[kk] = *(const short8*)(Qp + (size_t)lr * DHEAD + kk * 32 + q * 8);

        floatx4 accO[8];
#pragma unroll
        for (int d = 0; d < 8; ++d) accO[d] = zf4();
        float m_i[4] = {-1e30f, -1e30f, -1e30f, -1e30f};
        float l_i[4] = {0.f, 0.f, 0.f, 0.f};

        const int nkt = qt + 1;
        for (int kt = 0; kt < nkt; ++kt) {
            // stage K (64x128) and V^T (128x64) tiles
#pragma unroll
            for (int i = 0; i < 4; ++i) {
                int ci = i * 256 + t;
                int krow = ci >> 4, kc = (ci & 15) << 3;
                async16(Kp + (size_t)(kt * 64 + krow) * DHEAD + kc,
                        ldsK + (i * 256 + wave * 64) * 8);
                int dh = ci >> 3, vc = (ci & 7) << 3;
                async16(Vp + (size_t)dh * S_LEN + kt * 64 + vc,
                        ldsV + (i * 256 + wave * 64) * 8);
            }
            __syncthreads();

            // scores: 16 (queries) x 64 (keys) per wave
            floatx4 sc[4];
#pragma unroll
            for (int c = 0; c < 4; ++c) {
                sc[c] = zf4();
#pragma unroll
                for (int kk = 0; kk < 4; ++kk) {
                    short8 kb = *(const short8*)(ldsK + (c * 16 + lr) * DHEAD + kk * 32 + q * 8);
                    sc[c] = mfma16(qf[kk], kb, sc[c]);
                }
            }

            const bool diag = (kt == qt);
#pragma unroll
            for (int rr = 0; rr < 4; ++rr) {
                int ql = wave * 16 + q * 4 + rr;
                float mx = -1e30f;
#pragma unroll
                for (int c = 0; c < 4; ++c) {
                    float s = sc[c][rr] * SM_SCALE;
                    if (diag && (c * 16 + lr) > ql) s = -1e30f;
                    sc[c][rr] = s;
                    mx = fmaxf(mx, s);
                }
                mx = fmaxf(mx, __shfl_xor(mx, 1));
                mx = fmaxf(mx, __shfl_xor(mx, 2));
                mx = fmaxf(mx, __shfl_xor(mx, 4));
                mx = fmaxf(mx, __shfl_xor(mx, 8));
                float mnew = fmaxf(m_i[rr], mx);
                float alpha = __expf(m_i[rr] - mnew);
                m_i[rr] = mnew;
                float rs = 0.f;
#pragma unroll
                for (int c = 0; c < 4; ++c) {
                    float p = __expf(sc[c][rr] - mnew);
                    sc[c][rr] = p;
                    rs += p;
                }
                rs += __shfl_xor(rs, 1);
                rs += __shfl_xor(rs, 2);
                rs += __shfl_xor(rs, 4);
                rs += __shfl_xor(rs, 8);
                l_i[rr] = l_i[rr] * alpha + rs;
#pragma unroll
                for (int d = 0; d < 8; ++d) accO[d][rr] *= alpha;
            }

            // P -> LDS (per-wave strip, A-operand layout)
            u16* Pw = ldsP + wave * 1024;
#pragma unroll
            for (int c = 0; c < 4; ++c)
#pragma unroll
                for (int rr = 0; rr < 4; ++rr)
                    Pw[(q * 4 + rr) * 64 + c * 16 + lr] = f2bf(sc[c][rr]);

            // PV: O(16x128) += P(16x64) @ V(64x128)
#pragma unroll
            for (int kk2 = 0; kk2 < 2; ++kk2) {
                short8 pa = *(const short8*)(Pw + lr * 64 + kk2 * 32 + q * 8);
#pragma unroll
                for (int d = 0; d < 8; ++d) {
                    short8 vb = *(const short8*)(ldsV + (d * 16 + lr) * 64 + kk2 * 32 + q * 8);
                    accO[d] = mfma16(pa, vb, accO[d]);
                }
            }
            __syncthreads();
        }

        // epilogue: O / l -> Ob [token][h*128 + dh]
        const int tok0 = qt * 64 + wave * 16;
#pragma unroll
        for (int rr = 0; rr < 4; ++rr) {
            float inv = 1.0f / l_i[rr];
            size_t rowoff = ((size_t)(b * S_LEN + tok0 + q * 4 + rr)) * (NH * DHEAD) + h * DHEAD;
#pragma unroll
            for (int d = 0; d < 8; ++d)
                Ob[rowoff + d * 16 + lr] = f2bf(accO[d][rr] * inv);
        }
    }
}

extern "C" void kernel_launch(void* const* d_in, const int* in_sizes, int n_in,
                              void* d_out, int out_size, void* d_ws, size_t ws_size,
                              hipStream_t stream) {
    const float* X  = (const float*)d_in[0];
    const int* pos  = (const int*)d_in[1];
    const float* wq = (const float*)d_in[2];
    const float* wk = (const float*)d_in[3];
    const float* wv = (const float*)d_in[4];
    const float* wo = (const float*)d_in[5];
    float* out = (float*)d_out;

    char* w = (char*)d_ws;
    u16* Xbf    = (u16*)(w);                    // 4096*2048*2      = 16777216
    u16* Wqkv   = (u16*)(w + 16777216);         // 3072*2048*2      = 12582912
    u16* Wo     = (u16*)(w + 29360128);         // 2048*2048*2      =  8388608
    u16* Qb     = (u16*)(w + 37748736);         // 2*16*2048*128*2  = 16777216
    u16* Kb     = (u16*)(w + 54525952);         // 2*4*2048*128*2   =  4194304
    u16* Vt     = (u16*)(w + 58720256);         //                  =  4194304
    u16* Ob     = (u16*)(w + 62914560);         // 4096*2048*2      = 16777216
    float* cst  = (float*)(w + 79691776);       // 2048*64*4        =   524288
    float* snt  = (float*)(w + 80216064);       //                  =   524288

    cast_x_kernel<<<8192, 256, 0, stream>>>((const float4*)X, (ushort4*)Xbf);
    transpose_cast_kernel<<<dim3(64, 64), 256, 0, stream>>>(wq, Wqkv, 2048, 2048);
    transpose_cast_kernel<<<dim3(16, 64), 256, 0, stream>>>(wk, Wqkv + (size_t)2048 * 2048, 2048, 512);
    transpose_cast_kernel<<<dim3(16, 64), 256, 0, stream>>>(wv, Wqkv + (size_t)2560 * 2048, 2048, 512);
    transpose_cast_kernel<<<dim3(64, 64), 256, 0, stream>>>(wo, Wo, 2048, 2048);
    rope_tables_kernel<<<512, 256, 0, stream>>>(cst, snt);
    qkv_gemm_kernel<<<dim3(24, 32), 256, 0, stream>>>(Xbf, Wqkv, Qb, Kb, Vt);
    rope_apply_kernel<<<20480, 256, 0, stream>>>(Qb, Kb, pos, cst, snt);
    fa_kernel<<<512, 256, 0, stream>>>(Qb, Kb, Vt, Ob);
    out_gemm_kernel<<<dim3(16, 32), 256, 0, stream>>>(Ob, Wo, out);
}

// Round 2
// 354.401 us; speedup vs baseline: 1.1494x; 1.1494x over previous
//
#include <hip/hip_runtime.h>
#include <cmath>

typedef unsigned short u16;
typedef float floatx4 __attribute__((ext_vector_type(4)));
typedef short short8 __attribute__((ext_vector_type(8)));
typedef __bf16 bf16x8 __attribute__((ext_vector_type(8)));

#define GLOBAL_AS __attribute__((address_space(1)))
#define LDS_AS __attribute__((address_space(3)))

#define S_LEN 2048
#define D_MODEL 2048
#define NH 16
#define NKV 4
#define DHEAD 128
#define SM_SCALE 0.08838834764831843f
#define K2 (SM_SCALE * 1.4426950408889634f) /* SM_SCALE * log2(e) */

__device__ __forceinline__ u16 f2bf(float f) {
    unsigned int u = __builtin_bit_cast(unsigned int, f);
    u += 0x7fffu + ((u >> 16) & 1u);
    return (u16)(u >> 16);
}
// cheap round-to-nearest (no tie-to-even): 2 VALU ops, used in the fa inner loop
__device__ __forceinline__ u16 f2bfr(float f) {
    unsigned int u = __builtin_bit_cast(unsigned int, f);
    return (u16)((u + 0x8000u) >> 16);
}
__device__ __forceinline__ float bf2f(u16 x) {
    unsigned int u = ((unsigned int)x) << 16;
    return __builtin_bit_cast(float, u);
}
__device__ __forceinline__ floatx4 zf4() {
    floatx4 z; z[0] = 0.f; z[1] = 0.f; z[2] = 0.f; z[3] = 0.f; return z;
}
__device__ __forceinline__ floatx4 mfma16(short8 a, short8 b, floatx4 c) {
    return __builtin_amdgcn_mfma_f32_16x16x32_bf16(
        __builtin_bit_cast(bf16x8, a), __builtin_bit_cast(bf16x8, b), c, 0, 0, 0);
}
__device__ __forceinline__ void async16(const u16* g, u16* l) {
    __builtin_amdgcn_global_load_lds((GLOBAL_AS void*)g, (LDS_AS void*)l, 16, 0, 0);
}

// ---------------- cast X fp32 -> bf16 ----------------
__global__ void cast_x_kernel(const float4* __restrict__ in, ushort4* __restrict__ out) {
    int i = blockIdx.x * 256 + threadIdx.x;
    float4 v = in[i];
    ushort4 o;
    o.x = f2bf(v.x); o.y = f2bf(v.y); o.z = f2bf(v.z); o.w = f2bf(v.w);
    out[i] = o;
}

// ---------------- transpose + cast weights: in[R][C] fp32 -> out[C][R] bf16 ----------------
__global__ void transpose_cast_kernel(const float* __restrict__ in, u16* __restrict__ out,
                                      int R, int C) {
    __shared__ float tile[32][33];
    int tx = threadIdx.x & 31, ty = threadIdx.x >> 5;
    int bx = blockIdx.x * 32;  // over C
    int by = blockIdx.y * 32;  // over R
#pragma unroll
    for (int i = 0; i < 32; i += 8)
        tile[ty + i][tx] = in[(size_t)(by + ty + i) * C + bx + tx];
    __syncthreads();
#pragma unroll
    for (int i = 0; i < 32; i += 8)
        out[(size_t)(bx + ty + i) * R + by + tx] = f2bf(tile[tx][ty + i]);
}

// ---------------- rope tables (fp32-rounded angle, accurate trig) ----------------
__global__ void rope_tables_kernel(float* __restrict__ cs_tab, float* __restrict__ sn_tab) {
    int idx = blockIdx.x * 256 + threadIdx.x;  // 2048*64
    int p = idx >> 6, j = idx & 63;
    double e = (double)(2 * j) / 128.0;
    double invf = pow(10000.0, -e);
    float arg = (float)p * (float)invf;  // match reference's fp32 angle
    cs_tab[idx] = (float)cos((double)arg);
    sn_tab[idx] = (float)sin((double)arg);
}

// ---------------- apply RoPE in place on Q and K (vectorized x4) ----------------
__global__ void rope_apply_kernel(u16* __restrict__ Qb, u16* __restrict__ Kb,
                                  const int* __restrict__ pos,
                                  const float4* __restrict__ cs_tab,
                                  const float4* __restrict__ sn_tab) {
    int idx = blockIdx.x * 256 + threadIdx.x;  // 2*20*2048*16
    int j4 = idx & 15;
    int s = (idx >> 4) & 2047;
    int r = idx >> 15;        // b*20 + hh
    int hh = r % 20, b = r / 20;
    int p = pos[b * S_LEN + s];
    float4 cs = cs_tab[p * 16 + j4];
    float4 sn = sn_tab[p * 16 + j4];
    u16* base;
    if (hh < 16) base = Qb + (((size_t)(b * NH + hh)) * S_LEN + s) * DHEAD;
    else         base = Kb + (((size_t)(b * NKV + (hh - 16))) * S_LEN + s) * DHEAD;
    base += j4 * 4;
    ushort4 a = *(const ushort4*)(base);
    ushort4 c = *(const ushort4*)(base + 64);
    ushort4 oa, oc;
    float x1, x2;
    x1 = bf2f(a.x); x2 = bf2f(c.x); oa.x = f2bf(x1 * cs.x - x2 * sn.x); oc.x = f2bf(x2 * cs.x + x1 * sn.x);
    x1 = bf2f(a.y); x2 = bf2f(c.y); oa.y = f2bf(x1 * cs.y - x2 * sn.y); oc.y = f2bf(x2 * cs.y + x1 * sn.y);
    x1 = bf2f(a.z); x2 = bf2f(c.z); oa.z = f2bf(x1 * cs.z - x2 * sn.z); oc.z = f2bf(x2 * cs.z + x1 * sn.z);
    x1 = bf2f(a.w); x2 = bf2f(c.w); oa.w = f2bf(x1 * cs.w - x2 * sn.w); oc.w = f2bf(x2 * cs.w + x1 * sn.w);
    *(ushort4*)(base) = oa;
    *(ushort4*)(base + 64) = oc;
}

// ---------------- shared GEMM mainloop: A[M][K] bf16, Bt[N][K] bf16, 128x128 tile ----------------
// LDS layout: 128 rows x 32 u16, 4 chunks of 8 u16 per row, chunk slot c holds
// global chunk c ^ ((row>>1)&3)  (XOR swizzle -> conflict-free ds_read_b128).
__device__ __forceinline__ void gemm_mainloop(const u16* __restrict__ A,
                                              const u16* __restrict__ Bt,
                                              int K, u16* ldsA, u16* ldsB,
                                              floatx4 acc[4][4]) {
    const int t = threadIdx.x;
    const int lane = t & 63, wave = t >> 6;
    const int wr = wave >> 1, wc = wave & 1;
    const int lr = lane & 15, q = lane >> 4;
    const int m0 = blockIdx.y * 128, n0 = blockIdx.x * 128;
    const int swz = q ^ ((lr >> 1) & 3);

#pragma unroll
    for (int r = 0; r < 4; ++r)
#pragma unroll
        for (int c = 0; c < 4; ++c) acc[r][c] = zf4();

    for (int k0 = 0; k0 < K; k0 += 32) {
#pragma unroll
        for (int i = 0; i < 2; ++i) {
            int ci = i * 256 + t;
            int row = ci >> 2;
            int kc = ((ci & 3) ^ ((ci >> 3) & 3)) << 3;
            async16(A + (size_t)(m0 + row) * K + k0 + kc, ldsA + (i * 256 + wave * 64) * 8);
            async16(Bt + (size_t)(n0 + row) * K + k0 + kc, ldsB + (i * 256 + wave * 64) * 8);
        }
        __syncthreads();
        short8 af[4], bfr[4];
#pragma unroll
        for (int r = 0; r < 4; ++r)
            af[r] = *(const short8*)(ldsA + (wr * 64 + r * 16 + lr) * 32 + swz * 8);
#pragma unroll
        for (int c = 0; c < 4; ++c)
            bfr[c] = *(const short8*)(ldsB + (wc * 64 + c * 16 + lr) * 32 + swz * 8);
#pragma unroll
        for (int r = 0; r < 4; ++r)
#pragma unroll
            for (int c = 0; c < 4; ++c)
                acc[r][c] = mfma16(af[r], bfr[c], acc[r][c]);
        __syncthreads();
    }
}

// ---------------- QKV GEMM: scatter epilogue into Q/K/V^T bf16 ----------------
__global__ void qkv_gemm_kernel(const u16* __restrict__ A, const u16* __restrict__ Bt,
                                u16* __restrict__ Qb, u16* __restrict__ Kb,
                                u16* __restrict__ Vt) {
    __shared__ u16 ldsA[128 * 32];
    __shared__ u16 ldsB[128 * 32];
    floatx4 acc[4][4];
    gemm_mainloop(A, Bt, D_MODEL, ldsA, ldsB, acc);

    const int t = threadIdx.x, lane = t & 63, wave = t >> 6;
    const int wr = wave >> 1, wc = wave & 1, lr = lane & 15, q = lane >> 4;
    const int m0 = blockIdx.y * 128 + wr * 64, n0 = blockIdx.x * 128 + wc * 64;
#pragma unroll
    for (int r = 0; r < 4; ++r)
#pragma unroll
        for (int c = 0; c < 4; ++c) {
            int gc = n0 + c * 16 + lr;
#pragma unroll
            for (int rr = 0; rr < 4; ++rr) {
                int grow = m0 + r * 16 + q * 4 + rr;  // token
                int bb = grow >> 11, s = grow & 2047;
                u16 bv = f2bf(acc[r][c][rr]);
                int d = gc & 127;
                if (gc < 2048) {
                    int hh = gc >> 7;
                    Qb[(((size_t)(bb * NH + hh)) * S_LEN + s) * DHEAD + d] = bv;
                } else if (gc < 2560) {
                    int hh = (gc - 2048) >> 7;
                    Kb[(((size_t)(bb * NKV + hh)) * S_LEN + s) * DHEAD + d] = bv;
                } else {
                    int hh = (gc - 2560) >> 7;
                    Vt[(((size_t)(bb * NKV + hh)) * DHEAD + d) * S_LEN + s] = bv;
                }
            }
        }
}

// ---------------- out GEMM: fp32 epilogue to d_out ----------------
__global__ void out_gemm_kernel(const u16* __restrict__ A, const u16* __restrict__ Bt,
                                float* __restrict__ out) {
    __shared__ u16 ldsA[128 * 32];
    __shared__ u16 ldsB[128 * 32];
    floatx4 acc[4][4];
    gemm_mainloop(A, Bt, D_MODEL, ldsA, ldsB, acc);

    const int t = threadIdx.x, lane = t & 63, wave = t >> 6;
    const int wr = wave >> 1, wc = wave & 1, lr = lane & 15, q = lane >> 4;
    const int m0 = blockIdx.y * 128 + wr * 64, n0 = blockIdx.x * 128 + wc * 64;
#pragma unroll
    for (int r = 0; r < 4; ++r)
#pragma unroll
        for (int c = 0; c < 4; ++c) {
            int gc = n0 + c * 16 + lr;
#pragma unroll
            for (int rr = 0; rr < 4; ++rr) {
                int grow = m0 + r * 16 + q * 4 + rr;
                out[(size_t)grow * D_MODEL + gc] = acc[r][c][rr];
            }
        }
}

// ---------------- flash attention ----------------
// grid: 1024 blocks = qt(32, high bits) * bh(32, low bits); one 64-query tile per block.
// bh in low bits -> every XCD (bid%8 round-robin) sees all qt values -> balanced.
// LDS 40960 B -> 4 blocks/CU, 16 waves/CU.
// K tile: 64 rows x 128 (16 chunks), slot c holds global chunk c^(row&7).
// V tile: 128 rows(d) x 64 (8 chunks), same swizzle.
// P strip: per-wave 16 x 64 (8 chunks), same swizzle.
__global__ __launch_bounds__(256, 4) void fa_kernel(const u16* __restrict__ Qb,
                                                    const u16* __restrict__ Kb,
                                                    const u16* __restrict__ Vt,
                                                    u16* __restrict__ Ob) {
    __shared__ u16 ldsK[64 * 128];
    __shared__ u16 ldsV[128 * 64];
    __shared__ u16 ldsP[4 * 16 * 64];

    const int t = threadIdx.x, lane = t & 63, wave = t >> 6;
    const int lr = lane & 15, q = lane >> 4;
    const int swz = lr & 7;

    const int bid = blockIdx.x;
    const int qt = bid >> 5;
    const int bh = bid & 31;
    const int b = bh >> 4, h = bh & 15;
    const int kvh = h >> 2;

    const u16* Kp = Kb + (size_t)(b * NKV + kvh) * S_LEN * DHEAD;
    const u16* Vp = Vt + (size_t)(b * NKV + kvh) * DHEAD * S_LEN;
    const u16* Qp = Qb + ((size_t)((b * NH + h) * S_LEN) + qt * 64 + wave * 16) * DHEAD;

    short8 qf[4];
#pragma unroll
    for (int kk = 0; kk < 4; ++kk)
        qf[kk] = *(const short8*)(Qp + (size_t)lr * DHEAD + kk * 32 + q * 8);

    floatx4 accO[8];
#pragma unroll
    for (int d = 0; d < 8; ++d) accO[d] = zf4();
    float m_i[4] = {-3e38f, -3e38f, -3e38f, -3e38f};
    float l_i[4] = {0.f, 0.f, 0.f, 0.f};

    const int nkt = qt + 1;
    for (int kt = 0; kt < nkt; ++kt) {
        // stage K (64x128) and V^T (128x64) tiles, XOR-swizzled at 8-u16 chunk granularity
#pragma unroll
        for (int i = 0; i < 4; ++i) {
            int ci = i * 256 + t;
            int krow = ci >> 4, kc = ((ci & 15) ^ ((ci >> 4) & 7)) << 3;
            async16(Kp + (size_t)(kt * 64 + krow) * DHEAD + kc,
                    ldsK + (i * 256 + wave * 64) * 8);
            int dh = ci >> 3, vc = ((ci & 7) ^ ((ci >> 3) & 7)) << 3;
            async16(Vp + (size_t)dh * S_LEN + kt * 64 + vc,
                    ldsV + (i * 256 + wave * 64) * 8);
        }
        __syncthreads();

        // scores: 16 (queries) x 64 (keys) per wave  (raw, unscaled)
        floatx4 sc[4];
#pragma unroll
        for (int c = 0; c < 4; ++c) {
            sc[c] = zf4();
#pragma unroll
            for (int kk = 0; kk < 4; ++kk) {
                short8 kb = *(const short8*)(ldsK + (c * 16 + lr) * DHEAD +
                                             (((kk * 4 + q) ^ swz) << 3));
                sc[c] = mfma16(qf[kk], kb, sc[c]);
            }
        }

        const bool diag = (kt == qt);
#pragma unroll
        for (int rr = 0; rr < 4; ++rr) {
            int ql = wave * 16 + q * 4 + rr;
            float mx = -3e38f;
#pragma unroll
            for (int c = 0; c < 4; ++c) {
                float s = sc[c][rr];
                if (diag && (c * 16 + lr) > ql) s = -3e38f;
                sc[c][rr] = s;
                mx = fmaxf(mx, s);
            }
            mx = fmaxf(mx, __shfl_xor(mx, 1));
            mx = fmaxf(mx, __shfl_xor(mx, 2));
            mx = fmaxf(mx, __shfl_xor(mx, 4));
            mx = fmaxf(mx, __shfl_xor(mx, 8));
            float mnew = fmaxf(m_i[rr], mx);
            float mk = mnew * K2;
            float alpha = __builtin_amdgcn_exp2f(fmaf(m_i[rr], K2, -mk));
            m_i[rr] = mnew;
            float rs = 0.f;
#pragma unroll
            for (int c = 0; c < 4; ++c) {
                float p = __builtin_amdgcn_exp2f(fmaf(sc[c][rr], K2, -mk));
                sc[c][rr] = p;
                rs += p;
            }
            rs += __shfl_xor(rs, 1);
            rs += __shfl_xor(rs, 2);
            rs += __shfl_xor(rs, 4);
            rs += __shfl_xor(rs, 8);
            l_i[rr] = l_i[rr] * alpha + rs;
#pragma unroll
            for (int d = 0; d < 8; ++d) accO[d][rr] *= alpha;
        }

        // P -> LDS (per-wave strip, swizzled); wave-private, no barrier needed
        u16* Pw = ldsP + wave * 1024;
#pragma unroll
        for (int c = 0; c < 4; ++c)
#pragma unroll
            for (int rr = 0; rr < 4; ++rr) {
                int prow = q * 4 + rr;
                int pch = (c * 2 + (lr >> 3)) ^ (prow & 7);
                Pw[prow * 64 + pch * 8 + (lr & 7)] = f2bfr(sc[c][rr]);
            }

        // PV: O(16x128) += P(16x64) @ V(64x128)
#pragma unroll
        for (int kk2 = 0; kk2 < 2; ++kk2) {
            short8 pa = *(const short8*)(Pw + lr * 64 + (((kk2 * 4 + q) ^ swz) << 3));
#pragma unroll
            for (int d = 0; d < 8; ++d) {
                short8 vb = *(const short8*)(ldsV + (d * 16 + lr) * 64 +
                                             (((kk2 * 4 + q) ^ swz) << 3));
                accO[d] = mfma16(pa, vb, accO[d]);
            }
        }
        __syncthreads();
    }

    // epilogue: O / l -> Ob [token][h*128 + dh]
    const int tok0 = qt * 64 + wave * 16;
#pragma unroll
    for (int rr = 0; rr < 4; ++rr) {
        float inv = 1.0f / l_i[rr];
        size_t rowoff = ((size_t)(b * S_LEN + tok0 + q * 4 + rr)) * (NH * DHEAD) + h * DHEAD;
#pragma unroll
        for (int d = 0; d < 8; ++d)
            Ob[rowoff + d * 16 + lr] = f2bf(accO[d][rr] * inv);
    }
}

extern "C" void kernel_launch(void* const* d_in, const int* in_sizes, int n_in,
                              void* d_out, int out_size, void* d_ws, size_t ws_size,
                              hipStream_t stream) {
    const float* X  = (const float*)d_in[0];
    const int* pos  = (const int*)d_in[1];
    const float* wq = (const float*)d_in[2];
    const float* wk = (const float*)d_in[3];
    const float* wv = (const float*)d_in[4];
    const float* wo = (const float*)d_in[5];
    float* out = (float*)d_out;

    char* w = (char*)d_ws;
    u16* Xbf    = (u16*)(w);                    // 4096*2048*2      = 16777216
    u16* Wqkv   = (u16*)(w + 16777216);         // 3072*2048*2      = 12582912
    u16* Wo     = (u16*)(w + 29360128);         // 2048*2048*2      =  8388608
    u16* Qb     = (u16*)(w + 37748736);         // 2*16*2048*128*2  = 16777216
    u16* Kb     = (u16*)(w + 54525952);         // 2*4*2048*128*2   =  4194304
    u16* Vt     = (u16*)(w + 58720256);         //                  =  4194304
    u16* Ob     = (u16*)(w + 62914560);         // 4096*2048*2      = 16777216
    float* cst  = (float*)(w + 79691776);       // 2048*64*4        =   524288
    float* snt  = (float*)(w + 80216064);       //                  =   524288

    cast_x_kernel<<<8192, 256, 0, stream>>>((const float4*)X, (ushort4*)Xbf);
    transpose_cast_kernel<<<dim3(64, 64), 256, 0, stream>>>(wq, Wqkv, 2048, 2048);
    transpose_cast_kernel<<<dim3(16, 64), 256, 0, stream>>>(wk, Wqkv + (size_t)2048 * 2048, 2048, 512);
    transpose_cast_kernel<<<dim3(16, 64), 256, 0, stream>>>(wv, Wqkv + (size_t)2560 * 2048, 2048, 512);
    transpose_cast_kernel<<<dim3(64, 64), 256, 0, stream>>>(wo, Wo, 2048, 2048);
    rope_tables_kernel<<<512, 256, 0, stream>>>(cst, snt);
    qkv_gemm_kernel<<<dim3(24, 32), 256, 0, stream>>>(Xbf, Wqkv, Qb, Kb, Vt);
    rope_apply_kernel<<<5120, 256, 0, stream>>>(Qb, Kb, pos, (const float4*)cst, (const float4*)snt);
    fa_kernel<<<1024, 256, 0, stream>>>(Qb, Kb, Vt, Ob);
    out_gemm_kernel<<<dim3(16, 32), 256, 0, stream>>>(Ob, Wo, out);
}

// Round 3
// 326.336 us; speedup vs baseline: 1.2482x; 1.0860x over previous
//
#include <hip/hip_runtime.h>
#include <cmath>

typedef unsigned short u16;
typedef float floatx4 __attribute__((ext_vector_type(4)));
typedef short short8 __attribute__((ext_vector_type(8)));
typedef short short4v __attribute__((ext_vector_type(4)));
typedef __bf16 bf16x8 __attribute__((ext_vector_type(8)));

#define GLOBAL_AS __attribute__((address_space(1)))
#define LDS_AS __attribute__((address_space(3)))

#define S_LEN 2048
#define D_MODEL 2048
#define NH 16
#define NKV 4
#define DHEAD 128
#define SM_SCALE 0.08838834764831843f
#define K2 (SM_SCALE * 1.4426950408889634f) /* SM_SCALE * log2(e) */

__device__ __forceinline__ u16 f2bf(float f) {
    unsigned int u = __builtin_bit_cast(unsigned int, f);
    u += 0x7fffu + ((u >> 16) & 1u);
    return (u16)(u >> 16);
}
// cheap round-to-nearest (no tie-to-even): 2 VALU ops, used in the fa inner loop
__device__ __forceinline__ u16 f2bfr(float f) {
    unsigned int u = __builtin_bit_cast(unsigned int, f);
    return (u16)((u + 0x8000u) >> 16);
}
__device__ __forceinline__ float bf2f(u16 x) {
    unsigned int u = ((unsigned int)x) << 16;
    return __builtin_bit_cast(float, u);
}
__device__ __forceinline__ floatx4 zf4() {
    floatx4 z; z[0] = 0.f; z[1] = 0.f; z[2] = 0.f; z[3] = 0.f; return z;
}
__device__ __forceinline__ floatx4 mfma16(short8 a, short8 b, floatx4 c) {
    return __builtin_amdgcn_mfma_f32_16x16x32_bf16(
        __builtin_bit_cast(bf16x8, a), __builtin_bit_cast(bf16x8, b), c, 0, 0, 0);
}
// K=16 MFMA: A/B = 4 bf16 (2 VGPRs), k = quad*4 + j
__device__ __forceinline__ floatx4 mfma16k16(short4v a, short4v b, floatx4 c) {
    return __builtin_amdgcn_mfma_f32_16x16x16bf16_1k(a, b, c, 0, 0, 0);
}
__device__ __forceinline__ void async16(const u16* g, u16* l) {
    __builtin_amdgcn_global_load_lds((GLOBAL_AS void*)g, (LDS_AS void*)l, 16, 0, 0);
}

// ---------------- cast X fp32 -> bf16 ----------------
__global__ void cast_x_kernel(const float4* __restrict__ in, ushort4* __restrict__ out) {
    int i = blockIdx.x * 256 + threadIdx.x;
    float4 v = in[i];
    ushort4 o;
    o.x = f2bf(v.x); o.y = f2bf(v.y); o.z = f2bf(v.z); o.w = f2bf(v.w);
    out[i] = o;
}

// ---------------- transpose + cast weights: in[R][C] fp32 -> out[C][R] bf16 ----------------
__global__ void transpose_cast_kernel(const float* __restrict__ in, u16* __restrict__ out,
                                      int R, int C) {
    __shared__ float tile[32][33];
    int tx = threadIdx.x & 31, ty = threadIdx.x >> 5;
    int bx = blockIdx.x * 32;  // over C
    int by = blockIdx.y * 32;  // over R
#pragma unroll
    for (int i = 0; i < 32; i += 8)
        tile[ty + i][tx] = in[(size_t)(by + ty + i) * C + bx + tx];
    __syncthreads();
#pragma unroll
    for (int i = 0; i < 32; i += 8)
        out[(size_t)(bx + ty + i) * R + by + tx] = f2bf(tile[tx][ty + i]);
}

// ---------------- rope tables (fp32-rounded angle, accurate trig) ----------------
__global__ void rope_tables_kernel(float* __restrict__ cs_tab, float* __restrict__ sn_tab) {
    int idx = blockIdx.x * 256 + threadIdx.x;  // 2048*64
    int p = idx >> 6, j = idx & 63;
    double e = (double)(2 * j) / 128.0;
    double invf = pow(10000.0, -e);
    float arg = (float)p * (float)invf;  // match reference's fp32 angle
    cs_tab[idx] = (float)cos((double)arg);
    sn_tab[idx] = (float)sin((double)arg);
}

// ---------------- apply RoPE in place on Q and K (vectorized x4) ----------------
__global__ void rope_apply_kernel(u16* __restrict__ Qb, u16* __restrict__ Kb,
                                  const int* __restrict__ pos,
                                  const float4* __restrict__ cs_tab,
                                  const float4* __restrict__ sn_tab) {
    int idx = blockIdx.x * 256 + threadIdx.x;  // 2*20*2048*16
    int j4 = idx & 15;
    int s = (idx >> 4) & 2047;
    int r = idx >> 15;        // b*20 + hh
    int hh = r % 20, b = r / 20;
    int p = pos[b * S_LEN + s];
    float4 cs = cs_tab[p * 16 + j4];
    float4 sn = sn_tab[p * 16 + j4];
    u16* base;
    if (hh < 16) base = Qb + (((size_t)(b * NH + hh)) * S_LEN + s) * DHEAD;
    else         base = Kb + (((size_t)(b * NKV + (hh - 16))) * S_LEN + s) * DHEAD;
    base += j4 * 4;
    ushort4 a = *(const ushort4*)(base);
    ushort4 c = *(const ushort4*)(base + 64);
    ushort4 oa, oc;
    float x1, x2;
    x1 = bf2f(a.x); x2 = bf2f(c.x); oa.x = f2bf(x1 * cs.x - x2 * sn.x); oc.x = f2bf(x2 * cs.x + x1 * sn.x);
    x1 = bf2f(a.y); x2 = bf2f(c.y); oa.y = f2bf(x1 * cs.y - x2 * sn.y); oc.y = f2bf(x2 * cs.y + x1 * sn.y);
    x1 = bf2f(a.z); x2 = bf2f(c.z); oa.z = f2bf(x1 * cs.z - x2 * sn.z); oc.z = f2bf(x2 * cs.z + x1 * sn.z);
    x1 = bf2f(a.w); x2 = bf2f(c.w); oa.w = f2bf(x1 * cs.w - x2 * sn.w); oc.w = f2bf(x2 * cs.w + x1 * sn.w);
    *(ushort4*)(base) = oa;
    *(ushort4*)(base + 64) = oc;
}

// ---------------- shared GEMM mainloop: A[M][K] bf16, Bt[N][K] bf16, 128x128 tile ----------------
// LDS layout: 128 rows x 32 u16, 4 chunks of 8 u16 per row, chunk slot c holds
// global chunk c ^ ((row>>1)&3)  (XOR swizzle -> conflict-free ds_read_b128).
__device__ __forceinline__ void gemm_mainloop(const u16* __restrict__ A,
                                              const u16* __restrict__ Bt,
                                              int K, u16* ldsA, u16* ldsB,
                                              floatx4 acc[4][4]) {
    const int t = threadIdx.x;
    const int lane = t & 63, wave = t >> 6;
    const int wr = wave >> 1, wc = wave & 1;
    const int lr = lane & 15, q = lane >> 4;
    const int m0 = blockIdx.y * 128, n0 = blockIdx.x * 128;
    const int swz = q ^ ((lr >> 1) & 3);

#pragma unroll
    for (int r = 0; r < 4; ++r)
#pragma unroll
        for (int c = 0; c < 4; ++c) acc[r][c] = zf4();

    for (int k0 = 0; k0 < K; k0 += 32) {
#pragma unroll
        for (int i = 0; i < 2; ++i) {
            int ci = i * 256 + t;
            int row = ci >> 2;
            int kc = ((ci & 3) ^ ((ci >> 3) & 3)) << 3;
            async16(A + (size_t)(m0 + row) * K + k0 + kc, ldsA + (i * 256 + wave * 64) * 8);
            async16(Bt + (size_t)(n0 + row) * K + k0 + kc, ldsB + (i * 256 + wave * 64) * 8);
        }
        __syncthreads();
        short8 af[4], bfr[4];
#pragma unroll
        for (int r = 0; r < 4; ++r)
            af[r] = *(const short8*)(ldsA + (wr * 64 + r * 16 + lr) * 32 + swz * 8);
#pragma unroll
        for (int c = 0; c < 4; ++c)
            bfr[c] = *(const short8*)(ldsB + (wc * 64 + c * 16 + lr) * 32 + swz * 8);
#pragma unroll
        for (int r = 0; r < 4; ++r)
#pragma unroll
            for (int c = 0; c < 4; ++c)
                acc[r][c] = mfma16(af[r], bfr[c], acc[r][c]);
        __syncthreads();
    }
}

// ---------------- QKV GEMM: scatter epilogue into Q/K/V^T bf16 ----------------
__global__ void qkv_gemm_kernel(const u16* __restrict__ A, const u16* __restrict__ Bt,
                                u16* __restrict__ Qb, u16* __restrict__ Kb,
                                u16* __restrict__ Vt) {
    __shared__ u16 ldsA[128 * 32];
    __shared__ u16 ldsB[128 * 32];
    floatx4 acc[4][4];
    gemm_mainloop(A, Bt, D_MODEL, ldsA, ldsB, acc);

    const int t = threadIdx.x, lane = t & 63, wave = t >> 6;
    const int wr = wave >> 1, wc = wave & 1, lr = lane & 15, q = lane >> 4;
    const int m0 = blockIdx.y * 128 + wr * 64, n0 = blockIdx.x * 128 + wc * 64;
#pragma unroll
    for (int r = 0; r < 4; ++r)
#pragma unroll
        for (int c = 0; c < 4; ++c) {
            int gc = n0 + c * 16 + lr;
#pragma unroll
            for (int rr = 0; rr < 4; ++rr) {
                int grow = m0 + r * 16 + q * 4 + rr;  // token
                int bb = grow >> 11, s = grow & 2047;
                u16 bv = f2bf(acc[r][c][rr]);
                int d = gc & 127;
                if (gc < 2048) {
                    int hh = gc >> 7;
                    Qb[(((size_t)(bb * NH + hh)) * S_LEN + s) * DHEAD + d] = bv;
                } else if (gc < 2560) {
                    int hh = (gc - 2048) >> 7;
                    Kb[(((size_t)(bb * NKV + hh)) * S_LEN + s) * DHEAD + d] = bv;
                } else {
                    int hh = (gc - 2560) >> 7;
                    Vt[(((size_t)(bb * NKV + hh)) * DHEAD + d) * S_LEN + s] = bv;
                }
            }
        }
}

// ---------------- out GEMM: fp32 epilogue to d_out ----------------
__global__ void out_gemm_kernel(const u16* __restrict__ A, const u16* __restrict__ Bt,
                                float* __restrict__ out) {
    __shared__ u16 ldsA[128 * 32];
    __shared__ u16 ldsB[128 * 32];
    floatx4 acc[4][4];
    gemm_mainloop(A, Bt, D_MODEL, ldsA, ldsB, acc);

    const int t = threadIdx.x, lane = t & 63, wave = t >> 6;
    const int wr = wave >> 1, wc = wave & 1, lr = lane & 15, q = lane >> 4;
    const int m0 = blockIdx.y * 128 + wr * 64, n0 = blockIdx.x * 128 + wc * 64;
#pragma unroll
    for (int r = 0; r < 4; ++r)
#pragma unroll
        for (int c = 0; c < 4; ++c) {
            int gc = n0 + c * 16 + lr;
#pragma unroll
            for (int rr = 0; rr < 4; ++rr) {
                int grow = m0 + r * 16 + q * 4 + rr;
                out[(size_t)grow * D_MODEL + gc] = acc[r][c][rr];
            }
        }
}

// ---------------- flash attention (S^T formulation, register-resident P) ----------------
// grid: 1024 blocks = qt(32, high bits, REVERSED so heavy tiles launch first) * bh(32, low).
// Per wave: 16 queries (n = lane&15), 64 keys per k-tile.
// QK^T: S^T = K·Q^T via 16x16x32 -> C-layout (query=lane&15, key=quad*4+reg).
// Softmax: per-lane over 16 regs + shfl_xor(16,32); m/l are one scalar per lane.
// PV: O^T += V^T·P^T via 16x16x16 (k=quad*4+j) -- P^T fragment IS the softmaxed
// S^T register block; V^T A-frags are ds_read_b64 from swizzled ldsV. No ldsP.
__global__ __launch_bounds__(256, 4) void fa_kernel(const u16* __restrict__ Qb,
                                                    const u16* __restrict__ Kb,
                                                    const u16* __restrict__ Vt,
                                                    u16* __restrict__ Ob) {
    __shared__ u16 ldsK[64 * 128];
    __shared__ u16 ldsV[128 * 64];

    const int t = threadIdx.x, lane = t & 63, wave = t >> 6;
    const int lr = lane & 15, q = lane >> 4;
    const int swz = lr & 7;

    const int bid = blockIdx.x;
    const int qt = 31 - (bid >> 5);          // heavy tiles first
    const int bh = bid & 31;
    const int b = bh >> 4, h = bh & 15;
    const int kvh = h >> 2;

    const u16* Kp = Kb + (size_t)(b * NKV + kvh) * S_LEN * DHEAD;
    const u16* Vp = Vt + (size_t)(b * NKV + kvh) * DHEAD * S_LEN;
    const u16* Qp = Qb + ((size_t)((b * NH + h) * S_LEN) + qt * 64 + wave * 16) * DHEAD;

    short8 qf[4];  // B-operand: n = lane&15 = query, k = quad*8+j
#pragma unroll
    for (int kk = 0; kk < 4; ++kk)
        qf[kk] = *(const short8*)(Qp + (size_t)lr * DHEAD + kk * 32 + q * 8);

    floatx4 accO[8];  // O^T: (query=lane&15, d = dblk*16 + quad*4 + reg)
#pragma unroll
    for (int d = 0; d < 8; ++d) accO[d] = zf4();
    float m_i = -3e38f, l_i = 0.f;  // per-query scalars (query = wave*16+lr)

    const int nkt = qt + 1;
    for (int kt = 0; kt < nkt; ++kt) {
        // stage K (64x128) and V^T (128x64) tiles, XOR-swizzled at 8-u16 chunks
#pragma unroll
        for (int i = 0; i < 4; ++i) {
            int ci = i * 256 + t;
            int krow = ci >> 4, kc = ((ci & 15) ^ ((ci >> 4) & 7)) << 3;
            async16(Kp + (size_t)(kt * 64 + krow) * DHEAD + kc,
                    ldsK + (i * 256 + wave * 64) * 8);
            int dh = ci >> 3, vc = ((ci & 7) ^ ((ci >> 3) & 7)) << 3;
            async16(Vp + (size_t)dh * S_LEN + kt * 64 + vc,
                    ldsV + (i * 256 + wave * 64) * 8);
        }
        __syncthreads();

        // S^T: 64 keys (m, blocks c) x 16 queries (n) per wave
        floatx4 sc[4];
#pragma unroll
        for (int c = 0; c < 4; ++c) {
            sc[c] = zf4();
#pragma unroll
            for (int kk = 0; kk < 4; ++kk) {
                short8 kfr = *(const short8*)(ldsK + (c * 16 + lr) * DHEAD +
                                              (((kk * 4 + q) ^ swz) << 3));
                sc[c] = mfma16(kfr, qf[kk], sc[c]);
            }
        }

        if (kt == qt) {  // causal mask on the diagonal tile: key > query -> -inf
            const int qrow = wave * 16 + lr;
#pragma unroll
            for (int c = 0; c < 4; ++c)
#pragma unroll
                for (int rr = 0; rr < 4; ++rr)
                    if (c * 16 + q * 4 + rr > qrow) sc[c][rr] = -3e38f;
        }

        // online softmax, per lane (query fixed; keys split across regs + quads)
        float mx = -3e38f;
#pragma unroll
        for (int c = 0; c < 4; ++c)
#pragma unroll
            for (int rr = 0; rr < 4; ++rr) mx = fmaxf(mx, sc[c][rr]);
        mx = fmaxf(mx, __shfl_xor(mx, 16));
        mx = fmaxf(mx, __shfl_xor(mx, 32));
        float mnew = fmaxf(m_i, mx);
        float mk = mnew * K2;
        float alpha = __builtin_amdgcn_exp2f(fmaf(m_i, K2, -mk));
        m_i = mnew;
        float rs = 0.f;
#pragma unroll
        for (int c = 0; c < 4; ++c)
#pragma unroll
            for (int rr = 0; rr < 4; ++rr) {
                float p = __builtin_amdgcn_exp2f(fmaf(sc[c][rr], K2, -mk));
                sc[c][rr] = p;
                rs += p;
            }
        rs += __shfl_xor(rs, 16);
        rs += __shfl_xor(rs, 32);
        l_i = l_i * alpha + rs;
#pragma unroll
        for (int d = 0; d < 8; ++d) accO[d] *= alpha;

        // pack P^T fragments: B-operand of 16x16x16 (n=query=lane&15, k=quad*4+j)
        short4v pb[4];
#pragma unroll
        for (int c = 0; c < 4; ++c) {
            pb[c][0] = (short)f2bfr(sc[c][0]);
            pb[c][1] = (short)f2bfr(sc[c][1]);
            pb[c][2] = (short)f2bfr(sc[c][2]);
            pb[c][3] = (short)f2bfr(sc[c][3]);
        }

        // PV: O^T(128 x 16) += V^T(128 x 64) · P^T(64 x 16), 16-key steps
#pragma unroll
        for (int ks = 0; ks < 4; ++ks)
#pragma unroll
            for (int d = 0; d < 8; ++d) {
                short4v vf = *(const short4v*)(ldsV + (d * 16 + lr) * 64 +
                                               (((ks * 2 + (q >> 1)) ^ swz) << 3) +
                                               (q & 1) * 4);
                accO[d] = mfma16k16(vf, pb[ks], accO[d]);
            }
        __syncthreads();
    }

    // epilogue: O^T / l -> Ob [token][h*128 + d]; d contiguous per lane -> ushort4
    const int tok = qt * 64 + wave * 16 + lr;
    const float inv = 1.0f / l_i;
    u16* orow = Ob + ((size_t)(b * S_LEN + tok)) * (NH * DHEAD) + h * DHEAD + q * 4;
#pragma unroll
    for (int d = 0; d < 8; ++d) {
        ushort4 o;
        o.x = f2bf(accO[d][0] * inv);
        o.y = f2bf(accO[d][1] * inv);
        o.z = f2bf(accO[d][2] * inv);
        o.w = f2bf(accO[d][3] * inv);
        *(ushort4*)(orow + d * 16) = o;
    }
}

extern "C" void kernel_launch(void* const* d_in, const int* in_sizes, int n_in,
                              void* d_out, int out_size, void* d_ws, size_t ws_size,
                              hipStream_t stream) {
    const float* X  = (const float*)d_in[0];
    const int* pos  = (const int*)d_in[1];
    const float* wq = (const float*)d_in[2];
    const float* wk = (const float*)d_in[3];
    const float* wv = (const float*)d_in[4];
    const float* wo = (const float*)d_in[5];
    float* out = (float*)d_out;

    char* w = (char*)d_ws;
    u16* Xbf    = (u16*)(w);                    // 4096*2048*2      = 16777216
    u16* Wqkv   = (u16*)(w + 16777216);         // 3072*2048*2      = 12582912
    u16* Wo     = (u16*)(w + 29360128);         // 2048*2048*2      =  8388608
    u16* Qb     = (u16*)(w + 37748736);         // 2*16*2048*128*2  = 16777216
    u16* Kb     = (u16*)(w + 54525952);         // 2*4*2048*128*2   =  4194304
    u16* Vt     = (u16*)(w + 58720256);         //                  =  4194304
    u16* Ob     = (u16*)(w + 62914560);         // 4096*2048*2      = 16777216
    float* cst  = (float*)(w + 79691776);       // 2048*64*4        =   524288
    float* snt  = (float*)(w + 80216064);       //                  =   524288

    cast_x_kernel<<<8192, 256, 0, stream>>>((const float4*)X, (ushort4*)Xbf);
    transpose_cast_kernel<<<dim3(64, 64), 256, 0, stream>>>(wq, Wqkv, 2048, 2048);
    transpose_cast_kernel<<<dim3(16, 64), 256, 0, stream>>>(wk, Wqkv + (size_t)2048 * 2048, 2048, 512);
    transpose_cast_kernel<<<dim3(16, 64), 256, 0, stream>>>(wv, Wqkv + (size_t)2560 * 2048, 2048, 512);
    transpose_cast_kernel<<<dim3(64, 64), 256, 0, stream>>>(wo, Wo, 2048, 2048);
    rope_tables_kernel<<<512, 256, 0, stream>>>(cst, snt);
    qkv_gemm_kernel<<<dim3(24, 32), 256, 0, stream>>>(Xbf, Wqkv, Qb, Kb, Vt);
    rope_apply_kernel<<<5120, 256, 0, stream>>>(Qb, Kb, pos, (const float4*)cst, (const float4*)snt);
    fa_kernel<<<1024, 256, 0, stream>>>(Qb, Kb, Vt, Ob);
    out_gemm_kernel<<<dim3(16, 32), 256, 0, stream>>>(Ob, Wo, out);
}

// Round 4
// 312.686 us; speedup vs baseline: 1.3027x; 1.0437x over previous
//
#include <hip/hip_runtime.h>
#include <cmath>

typedef unsigned short u16;
typedef float floatx4 __attribute__((ext_vector_type(4)));
typedef short short8 __attribute__((ext_vector_type(8)));
typedef short short4v __attribute__((ext_vector_type(4)));
typedef __bf16 bf16x8 __attribute__((ext_vector_type(8)));

#define GLOBAL_AS __attribute__((address_space(1)))
#define LDS_AS __attribute__((address_space(3)))

#define S_LEN 2048
#define D_MODEL 2048
#define NH 16
#define NKV 4
#define DHEAD 128
#define SM_SCALE 0.08838834764831843f
#define K2 (SM_SCALE * 1.4426950408889634f) /* SM_SCALE * log2(e) */

__device__ __forceinline__ u16 f2bf(float f) {
    unsigned int u = __builtin_bit_cast(unsigned int, f);
    u += 0x7fffu + ((u >> 16) & 1u);
    return (u16)(u >> 16);
}
// cheap round-to-nearest (no tie-to-even): 2 VALU ops, used in the fa inner loop
__device__ __forceinline__ u16 f2bfr(float f) {
    unsigned int u = __builtin_bit_cast(unsigned int, f);
    return (u16)((u + 0x8000u) >> 16);
}
__device__ __forceinline__ float bf2f(u16 x) {
    unsigned int u = ((unsigned int)x) << 16;
    return __builtin_bit_cast(float, u);
}
__device__ __forceinline__ floatx4 zf4() {
    floatx4 z; z[0] = 0.f; z[1] = 0.f; z[2] = 0.f; z[3] = 0.f; return z;
}
__device__ __forceinline__ floatx4 mfma16(short8 a, short8 b, floatx4 c) {
    return __builtin_amdgcn_mfma_f32_16x16x32_bf16(
        __builtin_bit_cast(bf16x8, a), __builtin_bit_cast(bf16x8, b), c, 0, 0, 0);
}
// K=16 MFMA: A/B = 4 bf16 (2 VGPRs), k = quad*4 + j
__device__ __forceinline__ floatx4 mfma16k16(short4v a, short4v b, floatx4 c) {
    return __builtin_amdgcn_mfma_f32_16x16x16bf16_1k(a, b, c, 0, 0, 0);
}
__device__ __forceinline__ void async16(const u16* g, u16* l) {
    __builtin_amdgcn_global_load_lds((GLOBAL_AS void*)g, (LDS_AS void*)l, 16, 0, 0);
}

// ---------------- cast X fp32 -> bf16 ----------------
__global__ void cast_x_kernel(const float4* __restrict__ in, ushort4* __restrict__ out) {
    int i = blockIdx.x * 256 + threadIdx.x;
    float4 v = in[i];
    ushort4 o;
    o.x = f2bf(v.x); o.y = f2bf(v.y); o.z = f2bf(v.z); o.w = f2bf(v.w);
    out[i] = o;
}

// ---------------- transpose + cast weights: in[R][C] fp32 -> out[C][R] bf16 ----------------
__global__ void transpose_cast_kernel(const float* __restrict__ in, u16* __restrict__ out,
                                      int R, int C) {
    __shared__ float tile[32][33];
    int tx = threadIdx.x & 31, ty = threadIdx.x >> 5;
    int bx = blockIdx.x * 32;  // over C
    int by = blockIdx.y * 32;  // over R
#pragma unroll
    for (int i = 0; i < 32; i += 8)
        tile[ty + i][tx] = in[(size_t)(by + ty + i) * C + bx + tx];
    __syncthreads();
#pragma unroll
    for (int i = 0; i < 32; i += 8)
        out[(size_t)(bx + ty + i) * R + by + tx] = f2bf(tile[tx][ty + i]);
}

// ---------------- rope tables (fp32-rounded angle, accurate trig) ----------------
__global__ void rope_tables_kernel(float* __restrict__ cs_tab, float* __restrict__ sn_tab) {
    int idx = blockIdx.x * 256 + threadIdx.x;  // 2048*64
    int p = idx >> 6, j = idx & 63;
    double e = (double)(2 * j) / 128.0;
    double invf = pow(10000.0, -e);
    float arg = (float)p * (float)invf;  // match reference's fp32 angle
    cs_tab[idx] = (float)cos((double)arg);
    sn_tab[idx] = (float)sin((double)arg);
}

// ---------------- apply RoPE in place on Q and K (vectorized x4) ----------------
__global__ void rope_apply_kernel(u16* __restrict__ Qb, u16* __restrict__ Kb,
                                  const int* __restrict__ pos,
                                  const float4* __restrict__ cs_tab,
                                  const float4* __restrict__ sn_tab) {
    int idx = blockIdx.x * 256 + threadIdx.x;  // 2*20*2048*16
    int j4 = idx & 15;
    int s = (idx >> 4) & 2047;
    int r = idx >> 15;        // b*20 + hh
    int hh = r % 20, b = r / 20;
    int p = pos[b * S_LEN + s];
    float4 cs = cs_tab[p * 16 + j4];
    float4 sn = sn_tab[p * 16 + j4];
    u16* base;
    if (hh < 16) base = Qb + (((size_t)(b * NH + hh)) * S_LEN + s) * DHEAD;
    else         base = Kb + (((size_t)(b * NKV + (hh - 16))) * S_LEN + s) * DHEAD;
    base += j4 * 4;
    ushort4 a = *(const ushort4*)(base);
    ushort4 c = *(const ushort4*)(base + 64);
    ushort4 oa, oc;
    float x1, x2;
    x1 = bf2f(a.x); x2 = bf2f(c.x); oa.x = f2bf(x1 * cs.x - x2 * sn.x); oc.x = f2bf(x2 * cs.x + x1 * sn.x);
    x1 = bf2f(a.y); x2 = bf2f(c.y); oa.y = f2bf(x1 * cs.y - x2 * sn.y); oc.y = f2bf(x2 * cs.y + x1 * sn.y);
    x1 = bf2f(a.z); x2 = bf2f(c.z); oa.z = f2bf(x1 * cs.z - x2 * sn.z); oc.z = f2bf(x2 * cs.z + x1 * sn.z);
    x1 = bf2f(a.w); x2 = bf2f(c.w); oa.w = f2bf(x1 * cs.w - x2 * sn.w); oc.w = f2bf(x2 * cs.w + x1 * sn.w);
    *(ushort4*)(base) = oa;
    *(ushort4*)(base + 64) = oc;
}

// ---------------- shared GEMM mainloop: A[M][K] bf16, Bt[N][K] bf16, 128x128 tile ----------------
// BK=64: LDS 128 rows x 64 u16 per matrix (16 KB each), 8 chunks of 8 u16 per
// row; chunk slot c holds global chunk c ^ (row&7) -> conflict-free ds_read_b128.
// 32 MFMA per barrier pair (vs 16 at BK=32) halves the vmcnt-drain stalls.
__device__ __forceinline__ void gemm_mainloop(const u16* __restrict__ A,
                                              const u16* __restrict__ Bt,
                                              int K, u16* ldsA, u16* ldsB,
                                              floatx4 acc[4][4]) {
    const int t = threadIdx.x;
    const int lane = t & 63, wave = t >> 6;
    const int wr = wave >> 1, wc = wave & 1;
    const int lr = lane & 15, q = lane >> 4;
    const int m0 = blockIdx.y * 128, n0 = blockIdx.x * 128;
    const int swz = lr & 7;

#pragma unroll
    for (int r = 0; r < 4; ++r)
#pragma unroll
        for (int c = 0; c < 4; ++c) acc[r][c] = zf4();

    for (int k0 = 0; k0 < K; k0 += 64) {
#pragma unroll
        for (int i = 0; i < 4; ++i) {
            int ci = i * 256 + t;
            int row = ci >> 3;
            int kc = ((ci & 7) ^ (row & 7)) << 3;
            async16(A + (size_t)(m0 + row) * K + k0 + kc, ldsA + (i * 256 + wave * 64) * 8);
            async16(Bt + (size_t)(n0 + row) * K + k0 + kc, ldsB + (i * 256 + wave * 64) * 8);
        }
        __syncthreads();
#pragma unroll
        for (int ks = 0; ks < 2; ++ks) {
            short8 af[4], bfr[4];
#pragma unroll
            for (int r = 0; r < 4; ++r)
                af[r] = *(const short8*)(ldsA + (wr * 64 + r * 16 + lr) * 64 +
                                         (((ks * 4 + q) ^ swz) << 3));
#pragma unroll
            for (int c = 0; c < 4; ++c)
                bfr[c] = *(const short8*)(ldsB + (wc * 64 + c * 16 + lr) * 64 +
                                          (((ks * 4 + q) ^ swz) << 3));
#pragma unroll
            for (int r = 0; r < 4; ++r)
#pragma unroll
                for (int c = 0; c < 4; ++c)
                    acc[r][c] = mfma16(af[r], bfr[c], acc[r][c]);
        }
        __syncthreads();
    }
}

// ---------------- QKV GEMM: scatter epilogue into Q/K/V^T bf16 ----------------
// V^T is stored with the two 4-key halves of each 8-key chunk swapped for dims
// with bit3 set (s ^ 4 when d&8): lets fa's b64 V reads spread across all 32
// banks (the staging copy is verbatim, so the swap must live in global layout).
__global__ void qkv_gemm_kernel(const u16* __restrict__ A, const u16* __restrict__ Bt,
                                u16* __restrict__ Qb, u16* __restrict__ Kb,
                                u16* __restrict__ Vt) {
    __shared__ u16 ldsA[128 * 64];
    __shared__ u16 ldsB[128 * 64];
    floatx4 acc[4][4];
    gemm_mainloop(A, Bt, D_MODEL, ldsA, ldsB, acc);

    const int t = threadIdx.x, lane = t & 63, wave = t >> 6;
    const int wr = wave >> 1, wc = wave & 1, lr = lane & 15, q = lane >> 4;
    const int m0 = blockIdx.y * 128 + wr * 64, n0 = blockIdx.x * 128 + wc * 64;
#pragma unroll
    for (int r = 0; r < 4; ++r)
#pragma unroll
        for (int c = 0; c < 4; ++c) {
            int gc = n0 + c * 16 + lr;
#pragma unroll
            for (int rr = 0; rr < 4; ++rr) {
                int grow = m0 + r * 16 + q * 4 + rr;  // token
                int bb = grow >> 11, s = grow & 2047;
                u16 bv = f2bf(acc[r][c][rr]);
                int d = gc & 127;
                if (gc < 2048) {
                    int hh = gc >> 7;
                    Qb[(((size_t)(bb * NH + hh)) * S_LEN + s) * DHEAD + d] = bv;
                } else if (gc < 2560) {
                    int hh = (gc - 2048) >> 7;
                    Kb[(((size_t)(bb * NKV + hh)) * S_LEN + s) * DHEAD + d] = bv;
                } else {
                    int hh = (gc - 2560) >> 7;
                    int s2 = s ^ ((d & 8) >> 1);  // V half-spread (see header comment)
                    Vt[(((size_t)(bb * NKV + hh)) * DHEAD + d) * S_LEN + s2] = bv;
                }
            }
        }
}

// ---------------- out GEMM: fp32 epilogue to d_out ----------------
__global__ void out_gemm_kernel(const u16* __restrict__ A, const u16* __restrict__ Bt,
                                float* __restrict__ out) {
    __shared__ u16 ldsA[128 * 64];
    __shared__ u16 ldsB[128 * 64];
    floatx4 acc[4][4];
    gemm_mainloop(A, Bt, D_MODEL, ldsA, ldsB, acc);

    const int t = threadIdx.x, lane = t & 63, wave = t >> 6;
    const int wr = wave >> 1, wc = wave & 1, lr = lane & 15, q = lane >> 4;
    const int m0 = blockIdx.y * 128 + wr * 64, n0 = blockIdx.x * 128 + wc * 64;
#pragma unroll
    for (int r = 0; r < 4; ++r)
#pragma unroll
        for (int c = 0; c < 4; ++c) {
            int gc = n0 + c * 16 + lr;
#pragma unroll
            for (int rr = 0; rr < 4; ++rr) {
                int grow = m0 + r * 16 + q * 4 + rr;
                out[(size_t)grow * D_MODEL + gc] = acc[r][c][rr];
            }
        }
}

// ---------------- flash attention (S^T formulation, register-resident P) ----------------
// grid 1024: bid = (quarter r)<<8 | (p)<<3 | lo.  bh = r*8+lo; qt per quarter:
// {p, 31-p, p^16, 31-(p^16)} -> any CU's 4 co-resident blocks sum to 66 k-tiles
// (balanced makespan; the whole grid is resident so only balance matters).
// QK^T: S^T = K.Q^T via 16x16x32 -> C-layout (query=lane&15, key=quad*4+reg).
// PV: O^T += V^T.P^T via 16x16x16; P^T register fragment = softmaxed S^T block.
// V b64 reads use the half-spread layout (see qkv epilogue) -> conflict-free.
__global__ __launch_bounds__(256, 4) void fa_kernel(const u16* __restrict__ Qb,
                                                    const u16* __restrict__ Kb,
                                                    const u16* __restrict__ Vt,
                                                    u16* __restrict__ Ob) {
    __shared__ u16 ldsK[64 * 128];
    __shared__ u16 ldsV[128 * 64];

    const int t = threadIdx.x, lane = t & 63, wave = t >> 6;
    const int lr = lane & 15, q = lane >> 4;
    const int swz = lr & 7;

    const int bid = blockIdx.x;
    const int r4 = bid >> 8, j = bid & 255;
    const int p = j >> 3, lo = j & 7;
    const int bh = r4 * 8 + lo;
    int qt;
    if (r4 == 0) qt = p;
    else if (r4 == 1) qt = 31 - p;
    else if (r4 == 2) qt = p ^ 16;
    else qt = 31 - (p ^ 16);
    const int b = bh >> 4, h = bh & 15;
    const int kvh = h >> 2;

    const u16* Kp = Kb + (size_t)(b * NKV + kvh) * S_LEN * DHEAD;
    const u16* Vp = Vt + (size_t)(b * NKV + kvh) * DHEAD * S_LEN;
    const u16* Qp = Qb + ((size_t)((b * NH + h) * S_LEN) + qt * 64 + wave * 16) * DHEAD;

    short8 qf[4];  // B-operand: n = lane&15 = query, k = quad*8+j
#pragma unroll
    for (int kk = 0; kk < 4; ++kk)
        qf[kk] = *(const short8*)(Qp + (size_t)lr * DHEAD + kk * 32 + q * 8);

    floatx4 accO[8];  // O^T: (query=lane&15, d = dblk*16 + quad*4 + reg)
#pragma unroll
    for (int d = 0; d < 8; ++d) accO[d] = zf4();
    float m_i = -3e38f, l_i = 0.f;  // per-query scalars (query = wave*16+lr)

    const int nkt = qt + 1;
    for (int kt = 0; kt < nkt; ++kt) {
        // stage K (64x128) and V^T (128x64) tiles, XOR-swizzled at 8-u16 chunks
#pragma unroll
        for (int i = 0; i < 4; ++i) {
            int ci = i * 256 + t;
            int krow = ci >> 4, kc = ((ci & 15) ^ ((ci >> 4) & 7)) << 3;
            async16(Kp + (size_t)(kt * 64 + krow) * DHEAD + kc,
                    ldsK + (i * 256 + wave * 64) * 8);
            int dh = ci >> 3, vc = ((ci & 7) ^ ((ci >> 3) & 7)) << 3;
            async16(Vp + (size_t)dh * S_LEN + kt * 64 + vc,
                    ldsV + (i * 256 + wave * 64) * 8);
        }
        __syncthreads();

        // S^T: 64 keys (m, blocks c) x 16 queries (n) per wave
        floatx4 sc[4];
#pragma unroll
        for (int c = 0; c < 4; ++c) {
            sc[c] = zf4();
#pragma unroll
            for (int kk = 0; kk < 4; ++kk) {
                short8 kfr = *(const short8*)(ldsK + (c * 16 + lr) * DHEAD +
                                              (((kk * 4 + q) ^ swz) << 3));
                sc[c] = mfma16(kfr, qf[kk], sc[c]);
            }
        }

        if (kt == qt) {  // causal mask on the diagonal tile: key > query -> -inf
            const int qrow = wave * 16 + lr;
#pragma unroll
            for (int c = 0; c < 4; ++c)
#pragma unroll
                for (int rr = 0; rr < 4; ++rr)
                    if (c * 16 + q * 4 + rr > qrow) sc[c][rr] = -3e38f;
        }

        // online softmax, per lane (query fixed; keys split across regs + quads)
        float mx = -3e38f;
#pragma unroll
        for (int c = 0; c < 4; ++c)
#pragma unroll
            for (int rr = 0; rr < 4; ++rr) mx = fmaxf(mx, sc[c][rr]);
        mx = fmaxf(mx, __shfl_xor(mx, 16));
        mx = fmaxf(mx, __shfl_xor(mx, 32));
        float mnew = fmaxf(m_i, mx);
        float mk = mnew * K2;
        bool anyup = __any(mnew > m_i);
        float rs = 0.f;
#pragma unroll
        for (int c = 0; c < 4; ++c)
#pragma unroll
            for (int rr = 0; rr < 4; ++rr) {
                float pe = __builtin_amdgcn_exp2f(fmaf(sc[c][rr], K2, -mk));
                sc[c][rr] = pe;
                rs += pe;
            }
        rs += __shfl_xor(rs, 16);
        rs += __shfl_xor(rs, 32);
        if (anyup) {  // whole-wave skip: most k-tiles leave the running max unchanged
            float alpha = __builtin_amdgcn_exp2f(fmaf(m_i, K2, -mk));
            l_i = l_i * alpha + rs;
#pragma unroll
            for (int d = 0; d < 8; ++d) accO[d] *= alpha;
        } else {
            l_i += rs;
        }
        m_i = mnew;

        // pack P^T fragments: B-operand of 16x16x16 (n=query=lane&15, k=quad*4+j)
        short4v pb[4];
#pragma unroll
        for (int c = 0; c < 4; ++c) {
            pb[c][0] = (short)f2bfr(sc[c][0]);
            pb[c][1] = (short)f2bfr(sc[c][1]);
            pb[c][2] = (short)f2bfr(sc[c][2]);
            pb[c][3] = (short)f2bfr(sc[c][3]);
        }

        // PV: O^T(128 x 16) += V^T(128 x 64) . P^T(64 x 16), 16-key steps
#pragma unroll
        for (int ks = 0; ks < 4; ++ks)
#pragma unroll
            for (int d = 0; d < 8; ++d) {
                short4v vf = *(const short4v*)(ldsV + (d * 16 + lr) * 64 +
                                               (((ks * 2 + (q >> 1)) ^ swz) << 3) +
                                               (((q ^ (lr >> 3)) & 1) << 2));
                accO[d] = mfma16k16(vf, pb[ks], accO[d]);
            }
        __syncthreads();
    }

    // epilogue: O^T / l -> Ob [token][h*128 + d]; d contiguous per lane -> ushort4
    const int tok = qt * 64 + wave * 16 + lr;
    const float inv = 1.0f / l_i;
    u16* orow = Ob + ((size_t)(b * S_LEN + tok)) * (NH * DHEAD) + h * DHEAD + q * 4;
#pragma unroll
    for (int d = 0; d < 8; ++d) {
        ushort4 o;
        o.x = f2bf(accO[d][0] * inv);
        o.y = f2bf(accO[d][1] * inv);
        o.z = f2bf(accO[d][2] * inv);
        o.w = f2bf(accO[d][3] * inv);
        *(ushort4*)(orow + d * 16) = o;
    }
}

extern "C" void kernel_launch(void* const* d_in, const int* in_sizes, int n_in,
                              void* d_out, int out_size, void* d_ws, size_t ws_size,
                              hipStream_t stream) {
    const float* X  = (const float*)d_in[0];
    const int* pos  = (const int*)d_in[1];
    const float* wq = (const float*)d_in[2];
    const float* wk = (const float*)d_in[3];
    const float* wv = (const float*)d_in[4];
    const float* wo = (const float*)d_in[5];
    float* out = (float*)d_out;

    char* w = (char*)d_ws;
    u16* Xbf    = (u16*)(w);                    // 4096*2048*2      = 16777216
    u16* Wqkv   = (u16*)(w + 16777216);         // 3072*2048*2      = 12582912
    u16* Wo     = (u16*)(w + 29360128);         // 2048*2048*2      =  8388608
    u16* Qb     = (u16*)(w + 37748736);         // 2*16*2048*128*2  = 16777216
    u16* Kb     = (u16*)(w + 54525952);         // 2*4*2048*128*2   =  4194304
    u16* Vt     = (u16*)(w + 58720256);         //                  =  4194304
    u16* Ob     = (u16*)(w + 62914560);         // 4096*2048*2      = 16777216
    float* cst  = (float*)(w + 79691776);       // 2048*64*4        =   524288
    float* snt  = (float*)(w + 80216064);       //                  =   524288

    cast_x_kernel<<<8192, 256, 0, stream>>>((const float4*)X, (ushort4*)Xbf);
    transpose_cast_kernel<<<dim3(64, 64), 256, 0, stream>>>(wq, Wqkv, 2048, 2048);
    transpose_cast_kernel<<<dim3(16, 64), 256, 0, stream>>>(wk, Wqkv + (size_t)2048 * 2048, 2048, 512);
    transpose_cast_kernel<<<dim3(16, 64), 256, 0, stream>>>(wv, Wqkv + (size_t)2560 * 2048, 2048, 512);
    transpose_cast_kernel<<<dim3(64, 64), 256, 0, stream>>>(wo, Wo, 2048, 2048);
    rope_tables_kernel<<<512, 256, 0, stream>>>(cst, snt);
    qkv_gemm_kernel<<<dim3(24, 32), 256, 0, stream>>>(Xbf, Wqkv, Qb, Kb, Vt);
    rope_apply_kernel<<<5120, 256, 0, stream>>>(Qb, Kb, pos, (const float4*)cst, (const float4*)snt);
    fa_kernel<<<1024, 256, 0, stream>>>(Qb, Kb, Vt, Ob);
    out_gemm_kernel<<<dim3(16, 32), 256, 0, stream>>>(Ob, Wo, out);
}